// Round 1
// baseline (420.268 us; speedup 1.0000x reference)
//
#include <hip/hip_runtime.h>
#include <hip/hip_cooperative_groups.h>
#include <hip/hip_bf16.h>
#include <stdint.h>
#include <stddef.h>

typedef __bf16 bf16;
typedef __bf16 bf16x4 __attribute__((ext_vector_type(4)));
typedef __bf16 bf16x8 __attribute__((ext_vector_type(8)));
typedef float f32x4 __attribute__((ext_vector_type(4)));

#define BATCH 4096
#define KIH 7808          // Wih K
#define KTOT 7936         // 62 slots * 128 (h0 appended)
#define NG 512            // 4*LH gates
#define LH 128
#define HD 64
#define ED 128
#define SPLITK 4
#define GRID 512          // cooperative grid: 256 CUs x 2 blocks

// workspace layout (byte offsets)
#define OFF_WCAT 0u                 //  8,126,464  bf16 Wcat[512][7936]
#define OFF_GPART 8126464u          // 16,777,216  bf16 gpart[4][4096][512]
#define OFF_XT   24903680u          //  2,097,152  bf16 xtail[4096][256]
#define OFF_AB   27000832u          //     76,800  bf16 ab8[300][128]
#define OFF_MV   27077632u          //    230,400  bf16 mv8[900][128]
#define OFF_ADDR 27308032u          //  1,048,576  u32 addrs[4096][64]
#define OFF_H1B  28356608u          //  1,048,576  bf16 h1b (fallback path only)
#define OFF_W1F  29405184u          //     16,384  bf16 W1 fragments
#define OFF_W2F  29421568u          //     16,384  bf16 W2 fragments
#define OFF_WAF  29437952u          //      4,096  bf16 Wa fragments
#define OFF_NB   29442048u          //      2,048  f32 nbias[512]
// end: 29,444,096 B

// out layout: probs[B*9] | h1[B*128] | c1[B*128]
#define O_H1 (BATCH * 9)
#define O_C1 (BATCH * 9 + BATCH * LH)

// prep grid partition (virtual block ids)
#define PREP_BP 2048                 // build_pre: 2 rows/block
#define PREP_CW (PREP_BP + 512)      // convert_w
#define PREP_CE (PREP_CW + 150)      // convert_emb
#define PREP_TOT (PREP_CE + 1)       // + MLP fragment pack

// ---------------------------------------------------------------------------
typedef const __attribute__((address_space(1))) uint32_t* gas_ptr;
typedef __attribute__((address_space(3))) uint32_t* las_ptr;

__device__ __forceinline__ void async16(const void* g, void* l) {
    __builtin_amdgcn_global_load_lds((gas_ptr)g, (las_ptr)l, 16, 0, 0);
}

// ===========================================================================
// FALLBACK PATH: original 4-kernel pipeline (used only if cooperative launch
// is unavailable). Kept verbatim from the verified 167µs version.
// ===========================================================================
__global__ void prep(const int* __restrict__ ab_ids,
                     const int* __restrict__ mv_ids,
                     const float* __restrict__ numerical,
                     const float* __restrict__ h0,
                     const float* __restrict__ numW,
                     const float* __restrict__ numb,
                     const float* __restrict__ Wih,
                     const float* __restrict__ Whh,
                     const float* __restrict__ ab_emb,
                     const float* __restrict__ mv_emb,
                     const float* __restrict__ W1,
                     const float* __restrict__ W2,
                     const float* __restrict__ Wa,
                     uint8_t* __restrict__ ws) {
    const int bid = blockIdx.x;
    const int t = threadIdx.x;

    if (bid < PREP_BP) {
        bf16* xtail = (bf16*)(ws + OFF_XT);
        uint32_t* addrs = (uint32_t*)(ws + OFF_ADDR);
        const int h = t >> 7;
        const int th = t & 127;
        const int b = bid * 2 + h;

        __shared__ int ids[2][60];
        if (th < 60)
            ids[h][th] = (th < 12) ? ab_ids[b * 12 + th]
                                   : mv_ids[b * 48 + (th - 12)];

        const float v = (th < 84) ? numerical[(size_t)b * 84 + th] : 0.f;
        xtail[(size_t)b * 256 + th] = (bf16)v;
        xtail[(size_t)b * 256 + 128 + th] = (bf16)h0[(size_t)b * LH + th];
        __syncthreads();

        if (th < 64) {
            uint32_t off;
            if (th < 12) off = OFF_AB + (uint32_t)ids[h][th] * 256u;
            else if (th < 60) off = OFF_MV + (uint32_t)ids[h][th] * 256u;
            else if (th == 60) off = OFF_XT + (uint32_t)b * 512u;
            else if (th == 61) off = OFF_XT + (uint32_t)b * 512u + 256u;
            else off = OFF_XT;
            addrs[(size_t)b * 64 + th] = off;
        }
    } else if (bid < PREP_CW) {
        bf16* Wcat = (bf16*)(ws + OFF_WCAT);
        float* nbias = (float*)(ws + OFF_NB);
        const int n = bid - PREP_BP;

        __shared__ float wrow[128];
        __shared__ float nbs[128];
        if (t < 128) wrow[t] = Wih[(size_t)n * KIH + 7680 + t];
        else nbs[t - 128] = numb[t - 128];
        __syncthreads();

        const float* src_ih = Wih + (size_t)n * KIH;
        bf16* dst = Wcat + (size_t)n * KTOT;
        for (int k4 = t; k4 < 1920; k4 += 256) {
            const int k = k4 * 4;
            const float4 v = *(const float4*)(src_ih + k);
            bf16x4 o = {(bf16)v.x, (bf16)v.y, (bf16)v.z, (bf16)v.w};
            *(bf16x4*)(dst + k) = o;
        }
        if (t < 84) {
            float acc = 0.f;
#pragma unroll 4
            for (int e = 0; e < 128; ++e)
                acc += wrow[e] * numW[e * 84 + t];
            dst[7680 + t] = (bf16)acc;
        } else if (t < 128) {
            dst[7680 + t] = (bf16)0.f;
        } else {
            const int tt = t - 128;
            dst[KIH + tt] = (bf16)Whh[(size_t)n * LH + tt];
        }
        if (t == 255) {
            float a = 0.f;
#pragma unroll 4
            for (int e = 0; e < 128; ++e) a += wrow[e] * nbs[e];
            nbias[n] = a;
        }
    } else if (bid < PREP_CE) {
        bf16* ab8 = (bf16*)(ws + OFF_AB);
        bf16* mv8 = (bf16*)(ws + OFF_MV);
        const int i = ((bid - PREP_CW) * 256 + t) * 4;
        const bool isab = i < 300 * 128;
        const float4 v = isab ? *(const float4*)(ab_emb + i)
                              : *(const float4*)(mv_emb + (i - 300 * 128));
        bf16x4 o = {(bf16)v.x, (bf16)v.y, (bf16)v.z, (bf16)v.w};
        if (isab) *(bf16x4*)(ab8 + i) = o;
        else *(bf16x4*)(mv8 + (i - 300 * 128)) = o;
    } else {
        bf16* W1f = (bf16*)(ws + OFF_W1F);
        bf16* W2f = (bf16*)(ws + OFF_W2F);
        bf16* Waf = (bf16*)(ws + OFF_WAF);
        for (int e = t; e < 8192; e += 256) {
            const int j = e & 7, ln = (e >> 3) & 63, fid = e >> 9;
            const int kt = fid & 3, nt = fid >> 2;
            const int n = nt * 16 + (ln & 15);
            const int k = kt * 32 + (ln >> 4) * 8 + j;
            W1f[e] = (bf16)W1[n * 128 + k];
        }
        for (int e = t; e < 8192; e += 256) {
            const int j = e & 7, ln = (e >> 3) & 63, fid = e >> 9;
            const int kt = fid & 1, nt = fid >> 1;
            const int n = nt * 16 + (ln & 15);
            const int k = kt * 32 + (ln >> 4) * 8 + j;
            W2f[e] = (bf16)W2[n * 64 + k];
        }
        for (int e = t; e < 2048; e += 256) {
            const int j = e & 7, ln = (e >> 3) & 63, kt = e >> 9;
            const int n = ln & 15;
            const int k = kt * 32 + (ln >> 4) * 8 + j;
            Waf[e] = (n < 9) ? (bf16)Wa[n * 128 + k] : (bf16)0.f;
        }
    }
}

__global__ __launch_bounds__(256, 2) void gemm_gates(
    const uint8_t* __restrict__ wsbase,
    const bf16* __restrict__ Wcat,
    const uint32_t* __restrict__ addrs,
    bf16* __restrict__ gpart) {
    __shared__ bf16 As[2][128 * 64];
    __shared__ bf16 Bs[2][128 * 64];
    __shared__ uint32_t adr[17][128];

    const int tid = threadIdx.x;
    const int w = tid >> 6;
    const int lane = tid & 63;
    const int bm = blockIdx.x;
    const int bn = blockIdx.y;
    const int bz = blockIdx.z;
    const int kt_beg = bz * 31;
    const int kt_end = kt_beg + 31;

    const int s0 = kt_beg >> 1;
    const int ns = ((kt_end - 1) >> 1) - s0 + 1;
    for (int i = tid; i < ns * 128; i += 256) {
        adr[i >> 7][i & 127] =
            addrs[(size_t)(bm * 128 + (i & 127)) * 64 + s0 + (i >> 7)];
    }

    const int r_l = lane >> 3;
    const int sc16 = ((lane & 7) ^ r_l) * 16;

    const int wn = w & 1;
    const int wk = w >> 1;
    const int n0 = wn * 64;
    const int kk8 = wk * 4 + (lane >> 4);
    const int fl = lane & 15;

    f32x4 acc[8][4];
#pragma unroll
    for (int i = 0; i < 8; ++i)
#pragma unroll
        for (int j = 0; j < 4; ++j)
#pragma unroll
            for (int r = 0; r < 4; ++r) acc[i][j][r] = 0.f;

    __syncthreads();

    auto stage = [&](int kt, int pb) {
        const int k0 = kt * 64;
        const int sl = (kt >> 1) - s0;
        const int hb = (kt & 1) * 128;
#pragma unroll
        for (int j = 0; j < 4; ++j) {
            const int row = (w * 4 + j) * 8 + r_l;
            const uint8_t* gsrc = wsbase + adr[sl][row] + hb + sc16;
            async16(gsrc, (void*)&As[pb][((w * 4 + j) * 64 + lane) * 8]);
        }
#pragma unroll
        for (int j = 0; j < 4; ++j) {
            const int row = (w * 4 + j) * 8 + r_l;
            const bf16* gsrc = Wcat + (size_t)(bn * 128 + row) * KTOT + k0 + (sc16 >> 1);
            async16(gsrc, (void*)&Bs[pb][((w * 4 + j) * 64 + lane) * 8]);
        }
    };

    stage(kt_beg, 0);

    for (int kt = kt_beg; kt < kt_end; ++kt) {
        const int pb = (kt - kt_beg) & 1;
        __syncthreads();
        if (kt + 1 < kt_end) stage(kt + 1, pb ^ 1);

        const bf16* Ab = &As[pb][0];
        const bf16* Bb = &Bs[pb][0];

        bf16x8 bfr[4];
#pragma unroll
        for (int tj = 0; tj < 4; ++tj) {
            const int n = n0 + tj * 16 + fl;
            bfr[tj] = *(const bf16x8*)&Bb[n * 64 + ((kk8 ^ (n & 7)) * 8)];
        }
#pragma unroll
        for (int ti = 0; ti < 8; ++ti) {
            const int m = ti * 16 + fl;
            const bf16x8 af = *(const bf16x8*)&Ab[m * 64 + ((kk8 ^ (m & 7)) * 8)];
#pragma unroll
            for (int tj = 0; tj < 4; ++tj)
                acc[ti][tj] = __builtin_amdgcn_mfma_f32_16x16x32_bf16(
                    af, bfr[tj], acc[ti][tj], 0, 0, 0);
        }
    }

    __syncthreads();
    float* red = (wn == 0) ? (float*)&As[0][0] : (float*)&Bs[0][0];
    if (wk == 1) {
#pragma unroll
        for (int ti = 0; ti < 8; ++ti)
#pragma unroll
            for (int tj = 0; tj < 4; ++tj)
#pragma unroll
                for (int r = 0; r < 4; ++r)
                    red[((ti * 4 + tj) * 4 + r) * 64 + lane] = acc[ti][tj][r];
    }
    __syncthreads();

    if (wk == 0) {
        bf16* gdst = gpart + (size_t)bz * BATCH * NG;
        const int mlo = (lane >> 4) * 4;
#pragma unroll
        for (int ti = 0; ti < 8; ++ti)
#pragma unroll
            for (int tj = 0; tj < 4; ++tj) {
                const int mg = bm * 128 + ti * 16 + mlo;
                const int ng = bn * 128 + n0 + tj * 16 + fl;
                bf16* dst = gdst + (size_t)mg * NG + ng;
#pragma unroll
                for (int r = 0; r < 4; ++r)
                    dst[(size_t)r * NG] = (bf16)(
                        acc[ti][tj][r] + red[((ti * 4 + tj) * 4 + r) * 64 + lane]);
            }
    }
}

__global__ void reduce_lstm(const bf16* __restrict__ gpart,
                            const float* __restrict__ bih,
                            const float* __restrict__ bhh,
                            const float* __restrict__ nbias,
                            const float* __restrict__ c0,
                            float* __restrict__ out,
                            bf16* __restrict__ h1b) {
    const int t = threadIdx.x;
    const int b = blockIdx.x * 2 + (t >> 7);
    const int u = t & 127;

    float gv[4];
#pragma unroll
    for (int q = 0; q < 4; ++q)
        gv[q] = bih[q * 128 + u] + bhh[q * 128 + u] + nbias[q * 128 + u];
#pragma unroll
    for (int z = 0; z < SPLITK; ++z) {
        const bf16* gz = gpart + ((size_t)z * BATCH + b) * NG + u;
#pragma unroll
        for (int q = 0; q < 4; ++q) gv[q] += (float)gz[q * 128];
    }

    const float iv = 1.f / (1.f + __expf(-gv[0]));
    const float fv = 1.f / (1.f + __expf(-gv[1]));
    const float gg = tanhf(gv[2]);
    const float ov = 1.f / (1.f + __expf(-gv[3]));
    const float c1 = fv * c0[(size_t)b * LH + u] + iv * gg;
    const float h1 = ov * tanhf(c1);

    out[O_H1 + (size_t)b * LH + u] = h1;
    out[O_C1 + (size_t)b * LH + u] = c1;
    h1b[(size_t)b * LH + u] = (bf16)h1;
}

__global__ __launch_bounds__(64) void mlp_head(
    const bf16* __restrict__ h1b, const float* __restrict__ mask,
    const bf16* __restrict__ W1f, const bf16* __restrict__ W2f,
    const bf16* __restrict__ Waf,
    const float* __restrict__ b1, const float* __restrict__ b2,
    const float* __restrict__ ba,
    float* __restrict__ out) {
    __shared__ bf16 uS[16 * 64];
    __shared__ bf16 fS[16 * 128];

    const int lane = threadIdx.x;
    const int b0 = blockIdx.x * 16;
    const int nl = lane & 15, kg = lane >> 4;

    bf16x8 ah[4];
#pragma unroll
    for (int kt = 0; kt < 4; ++kt)
        ah[kt] = *(const bf16x8*)&h1b[(size_t)(b0 + nl) * 128 + kt * 32 + kg * 8];

#pragma unroll
    for (int nt = 0; nt < 4; ++nt) {
        f32x4 a = {0.f, 0.f, 0.f, 0.f};
#pragma unroll
        for (int kt = 0; kt < 4; ++kt)
            a = __builtin_amdgcn_mfma_f32_16x16x32_bf16(
                ah[kt], *(const bf16x8*)&W1f[((nt * 4 + kt) * 64 + lane) * 8],
                a, 0, 0, 0);
        const int n = nt * 16 + nl;
        const float bb = b1[n];
#pragma unroll
        for (int r = 0; r < 4; ++r)
            uS[(kg * 4 + r) * 64 + n] = (bf16)fmaxf(a[r] + bb, 0.f);
    }
    __syncthreads();

    bf16x8 au[2];
#pragma unroll
    for (int kt = 0; kt < 2; ++kt)
        au[kt] = *(const bf16x8*)&uS[nl * 64 + kt * 32 + kg * 8];

#pragma unroll
    for (int nt = 0; nt < 8; ++nt) {
        f32x4 a = {0.f, 0.f, 0.f, 0.f};
#pragma unroll
        for (int kt = 0; kt < 2; ++kt)
            a = __builtin_amdgcn_mfma_f32_16x16x32_bf16(
                au[kt], *(const bf16x8*)&W2f[((nt * 2 + kt) * 64 + lane) * 8],
                a, 0, 0, 0);
        const int n = nt * 16 + nl;
        const float bb = b2[n];
#pragma unroll
        for (int r = 0; r < 4; ++r)
            fS[(kg * 4 + r) * 128 + n] = (bf16)(a[r] + bb);
    }
    __syncthreads();

    bf16x8 afr[4];
#pragma unroll
    for (int kt = 0; kt < 4; ++kt)
        afr[kt] = *(const bf16x8*)&fS[nl * 128 + kt * 32 + kg * 8];

    f32x4 lg4 = {0.f, 0.f, 0.f, 0.f};
#pragma unroll
    for (int kt = 0; kt < 4; ++kt)
        lg4 = __builtin_amdgcn_mfma_f32_16x16x32_bf16(
            afr[kt], *(const bf16x8*)&Waf[(kt * 64 + lane) * 8], lg4, 0, 0, 0);

    const float bav = (nl < 9) ? ba[nl] : 0.f;

#pragma unroll
    for (int r = 0; r < 4; ++r) {
        const int b = b0 + kg * 4 + r;
        float lg = (nl < 9) ? lg4[r] + bav : -1e30f;
        float mx = lg;
#pragma unroll
        for (int off = 1; off < 16; off <<= 1)
            mx = fmaxf(mx, __shfl_xor(mx, off, 64));
        const float e = (nl < 9) ? __expf(lg - mx) : 0.f;
        const float mv = (nl < 9) ? mask[(size_t)b * 9 + nl] : 0.f;
        float tot = e, ms = e * mv;
#pragma unroll
        for (int off = 1; off < 16; off <<= 1) {
            tot += __shfl_xor(tot, off, 64);
            ms += __shfl_xor(ms, off, 64);
        }
        if (nl < 9)
            out[(size_t)b * 9 + nl] = (ms > 0.f) ? e * mv / ms : e / tot;
    }
}

// ===========================================================================
// COOPERATIVE FUSED KERNEL: prep | grid.sync | gemm | grid.sync | tail.
// 512 blocks x 256 threads = exactly 2 blocks/CU at 74KB LDS.
// Tail fuses reduce_lstm + mlp_head (16 rows/block on bid<256): 4-wave
// vectorized gate reduction + LSTM -> h1 in LDS -> single-wave MFMA MLP.
// ===========================================================================
__global__ __launch_bounds__(256, 2) void fused(
    const int* __restrict__ ab_ids, const int* __restrict__ mv_ids,
    const float* __restrict__ numerical, const float* __restrict__ mask,
    const float* __restrict__ h0, const float* __restrict__ c0,
    const float* __restrict__ ab_emb, const float* __restrict__ mv_emb,
    const float* __restrict__ numW, const float* __restrict__ numb,
    const float* __restrict__ Wih, const float* __restrict__ Whh,
    const float* __restrict__ bih, const float* __restrict__ bhh,
    const float* __restrict__ W1, const float* __restrict__ b1,
    const float* __restrict__ W2, const float* __restrict__ b2,
    const float* __restrict__ Wa, const float* __restrict__ ba,
    uint8_t* __restrict__ ws, float* __restrict__ out) {

    __shared__ bf16 As[2][128 * 64];    // 32 KB (also: prep wrow/nbs, tail hS)
    __shared__ bf16 Bs[2][128 * 64];    // 32 KB (also: tail uS/fS)
    __shared__ uint32_t adr[17][128];   // 8.5 KB (also: prep ids scratch)

    const int bid = blockIdx.x;
    const int t = threadIdx.x;
    cooperative_groups::grid_group grid = cooperative_groups::this_grid();

    // ---------------- phase P: prep (2711 virtual blocks over 512) ---------
    for (int vb = bid; vb < PREP_TOT; vb += GRID) {
        if (vb < PREP_BP) {
            bf16* xtail = (bf16*)(ws + OFF_XT);
            uint32_t* addrs = (uint32_t*)(ws + OFF_ADDR);
            int* ids = (int*)&adr[0][0];             // [2][60] scratch
            const int h = t >> 7;
            const int th = t & 127;
            const int b = vb * 2 + h;

            if (th < 60)
                ids[h * 60 + th] = (th < 12) ? ab_ids[b * 12 + th]
                                             : mv_ids[b * 48 + (th - 12)];

            const float v = (th < 84) ? numerical[(size_t)b * 84 + th] : 0.f;
            xtail[(size_t)b * 256 + th] = (bf16)v;
            xtail[(size_t)b * 256 + 128 + th] = (bf16)h0[(size_t)b * LH + th];
            __syncthreads();

            if (th < 64) {
                uint32_t off;
                if (th < 12) off = OFF_AB + (uint32_t)ids[h * 60 + th] * 256u;
                else if (th < 60) off = OFF_MV + (uint32_t)ids[h * 60 + th] * 256u;
                else if (th == 60) off = OFF_XT + (uint32_t)b * 512u;
                else if (th == 61) off = OFF_XT + (uint32_t)b * 512u + 256u;
                else off = OFF_XT;
                addrs[(size_t)b * 64 + th] = off;
            }
        } else if (vb < PREP_CW) {
            bf16* Wcat = (bf16*)(ws + OFF_WCAT);
            float* nbias = (float*)(ws + OFF_NB);
            const int n = vb - PREP_BP;
            float* wrow = (float*)&As[0][0];         // 128 f32 scratch
            float* nbs = wrow + 128;

            if (t < 128) wrow[t] = Wih[(size_t)n * KIH + 7680 + t];
            else if (t < 256) nbs[t - 128] = numb[t - 128];
            __syncthreads();

            const float* src_ih = Wih + (size_t)n * KIH;
            bf16* dst = Wcat + (size_t)n * KTOT;
            for (int k4 = t; k4 < 1920; k4 += 256) {
                const int k = k4 * 4;
                const float4 v = *(const float4*)(src_ih + k);
                bf16x4 o = {(bf16)v.x, (bf16)v.y, (bf16)v.z, (bf16)v.w};
                *(bf16x4*)(dst + k) = o;
            }
            if (t < 84) {
                float acc = 0.f;
#pragma unroll 4
                for (int e = 0; e < 128; ++e)
                    acc += wrow[e] * numW[e * 84 + t];
                dst[7680 + t] = (bf16)acc;
            } else if (t < 128) {
                dst[7680 + t] = (bf16)0.f;
            } else {
                const int tt = t - 128;
                dst[KIH + tt] = (bf16)Whh[(size_t)n * LH + tt];
            }
            if (t == 255) {
                float a = 0.f;
#pragma unroll 4
                for (int e = 0; e < 128; ++e) a += wrow[e] * nbs[e];
                nbias[n] = a;
            }
        } else if (vb < PREP_CE) {
            bf16* ab8 = (bf16*)(ws + OFF_AB);
            bf16* mv8 = (bf16*)(ws + OFF_MV);
            const int i = ((vb - PREP_CW) * 256 + t) * 4;
            const bool isab = i < 300 * 128;
            const float4 v = isab ? *(const float4*)(ab_emb + i)
                                  : *(const float4*)(mv_emb + (i - 300 * 128));
            bf16x4 o = {(bf16)v.x, (bf16)v.y, (bf16)v.z, (bf16)v.w};
            if (isab) *(bf16x4*)(ab8 + i) = o;
            else *(bf16x4*)(mv8 + (i - 300 * 128)) = o;
        } else {
            bf16* W1f = (bf16*)(ws + OFF_W1F);
            bf16* W2f = (bf16*)(ws + OFF_W2F);
            bf16* Waf = (bf16*)(ws + OFF_WAF);
            for (int e = t; e < 8192; e += 256) {
                const int j = e & 7, ln = (e >> 3) & 63, fid = e >> 9;
                const int kt = fid & 3, nt = fid >> 2;
                const int n = nt * 16 + (ln & 15);
                const int k = kt * 32 + (ln >> 4) * 8 + j;
                W1f[e] = (bf16)W1[n * 128 + k];
            }
            for (int e = t; e < 8192; e += 256) {
                const int j = e & 7, ln = (e >> 3) & 63, fid = e >> 9;
                const int kt = fid & 1, nt = fid >> 1;
                const int n = nt * 16 + (ln & 15);
                const int k = kt * 32 + (ln >> 4) * 8 + j;
                W2f[e] = (bf16)W2[n * 64 + k];
            }
            for (int e = t; e < 2048; e += 256) {
                const int j = e & 7, ln = (e >> 3) & 63, kt = e >> 9;
                const int n = ln & 15;
                const int k = kt * 32 + (ln >> 4) * 8 + j;
                Waf[e] = (n < 9) ? (bf16)Wa[n * 128 + k] : (bf16)0.f;
            }
        }
        __syncthreads();   // protect shared scratch reuse across units
    }

    __threadfence();
    grid.sync();

    // ---------------- phase G: gemm (identical tiling to gemm_gates) ------
    {
        const uint8_t* wsbase = ws;
        const bf16* Wcat = (const bf16*)(ws + OFF_WCAT);
        const uint32_t* addrs = (const uint32_t*)(ws + OFF_ADDR);
        bf16* gpart = (bf16*)(ws + OFF_GPART);

        const int w = t >> 6;
        const int lane = t & 63;
        const int bm = bid & 31;
        const int bn = (bid >> 5) & 3;
        const int bz = bid >> 7;
        const int kt_beg = bz * 31;
        const int kt_end = kt_beg + 31;

        const int s0 = kt_beg >> 1;
        const int ns = ((kt_end - 1) >> 1) - s0 + 1;
        for (int i = t; i < ns * 128; i += 256) {
            adr[i >> 7][i & 127] =
                addrs[(size_t)(bm * 128 + (i & 127)) * 64 + s0 + (i >> 7)];
        }

        const int r_l = lane >> 3;
        const int sc16 = ((lane & 7) ^ r_l) * 16;

        const int wn = w & 1;
        const int wk = w >> 1;
        const int n0 = wn * 64;
        const int kk8 = wk * 4 + (lane >> 4);
        const int fl = lane & 15;

        f32x4 acc[8][4];
#pragma unroll
        for (int i = 0; i < 8; ++i)
#pragma unroll
            for (int j = 0; j < 4; ++j)
#pragma unroll
                for (int r = 0; r < 4; ++r) acc[i][j][r] = 0.f;

        __syncthreads();   // adr visible

        auto stage = [&](int kt, int pb) {
            const int k0 = kt * 64;
            const int sl = (kt >> 1) - s0;
            const int hb = (kt & 1) * 128;
#pragma unroll
            for (int j = 0; j < 4; ++j) {
                const int row = (w * 4 + j) * 8 + r_l;
                const uint8_t* gsrc = wsbase + adr[sl][row] + hb + sc16;
                async16(gsrc, (void*)&As[pb][((w * 4 + j) * 64 + lane) * 8]);
            }
#pragma unroll
            for (int j = 0; j < 4; ++j) {
                const int row = (w * 4 + j) * 8 + r_l;
                const bf16* gsrc = Wcat + (size_t)(bn * 128 + row) * KTOT + k0 + (sc16 >> 1);
                async16(gsrc, (void*)&Bs[pb][((w * 4 + j) * 64 + lane) * 8]);
            }
        };

        stage(kt_beg, 0);

        for (int kt = kt_beg; kt < kt_end; ++kt) {
            const int pb = (kt - kt_beg) & 1;
            __syncthreads();
            if (kt + 1 < kt_end) stage(kt + 1, pb ^ 1);

            const bf16* Ab = &As[pb][0];
            const bf16* Bb = &Bs[pb][0];

            bf16x8 bfr[4];
#pragma unroll
            for (int tj = 0; tj < 4; ++tj) {
                const int n = n0 + tj * 16 + fl;
                bfr[tj] = *(const bf16x8*)&Bb[n * 64 + ((kk8 ^ (n & 7)) * 8)];
            }
#pragma unroll
            for (int ti = 0; ti < 8; ++ti) {
                const int m = ti * 16 + fl;
                const bf16x8 af = *(const bf16x8*)&Ab[m * 64 + ((kk8 ^ (m & 7)) * 8)];
#pragma unroll
                for (int tj = 0; tj < 4; ++tj)
                    acc[ti][tj] = __builtin_amdgcn_mfma_f32_16x16x32_bf16(
                        af, bfr[tj], acc[ti][tj], 0, 0, 0);
            }
        }

        __syncthreads();
        float* red = (wn == 0) ? (float*)&As[0][0] : (float*)&Bs[0][0];
        if (wk == 1) {
#pragma unroll
            for (int ti = 0; ti < 8; ++ti)
#pragma unroll
                for (int tj = 0; tj < 4; ++tj)
#pragma unroll
                    for (int r = 0; r < 4; ++r)
                        red[((ti * 4 + tj) * 4 + r) * 64 + lane] = acc[ti][tj][r];
        }
        __syncthreads();

        if (wk == 0) {
            bf16* gdst = gpart + (size_t)bz * BATCH * NG;
            const int mlo = (lane >> 4) * 4;
#pragma unroll
            for (int ti = 0; ti < 8; ++ti)
#pragma unroll
                for (int tj = 0; tj < 4; ++tj) {
                    const int mg = bm * 128 + ti * 16 + mlo;
                    const int ng = bn * 128 + n0 + tj * 16 + fl;
                    bf16* dst = gdst + (size_t)mg * NG + ng;
#pragma unroll
                    for (int r = 0; r < 4; ++r)
                        dst[(size_t)r * NG] = (bf16)(
                            acc[ti][tj][r] + red[((ti * 4 + tj) * 4 + r) * 64 + lane]);
                }
        }
    }

    __threadfence();
    grid.sync();

    // ---------------- phase T: reduce + LSTM + MLP head (bid < 256) -------
    if (bid < 256) {
        const bf16* gpart = (const bf16*)(ws + OFF_GPART);
        const float* nbias = (const float*)(ws + OFF_NB);
        bf16* hS = (bf16*)&As[0][0];        // 16 x 128 bf16
        bf16* uS = (bf16*)&Bs[0][0];        // 16 x 64 bf16
        bf16* fS = uS + 16 * 64;            // 16 x 128 bf16

        // --- A: gate reduction + LSTM, all 4 waves, 8 units/thread ---
        {
            const int r = t >> 4;               // row 0..15
            const int uc = (t & 15) * 8;        // unit chunk
            const int b = bid * 16 + r;

            float gv[4][8];
#pragma unroll
            for (int q = 0; q < 4; ++q)
#pragma unroll
                for (int hh = 0; hh < 2; ++hh) {
                    const f32x4 va = *(const f32x4*)(bih + q * 128 + uc + hh * 4);
                    const f32x4 vb = *(const f32x4*)(bhh + q * 128 + uc + hh * 4);
                    const f32x4 vn = *(const f32x4*)(nbias + q * 128 + uc + hh * 4);
#pragma unroll
                    for (int j = 0; j < 4; ++j)
                        gv[q][hh * 4 + j] = va[j] + vb[j] + vn[j];
                }
#pragma unroll
            for (int z = 0; z < SPLITK; ++z) {
                const bf16* gz = gpart + ((size_t)z * BATCH + b) * NG;
#pragma unroll
                for (int q = 0; q < 4; ++q) {
                    const bf16x8 v = *(const bf16x8*)(gz + q * 128 + uc);
#pragma unroll
                    for (int j = 0; j < 8; ++j) gv[q][j] += (float)v[j];
                }
            }

            const f32x4 c0a = *(const f32x4*)(c0 + (size_t)b * LH + uc);
            const f32x4 c0b = *(const f32x4*)(c0 + (size_t)b * LH + uc + 4);
            float h1v[8], c1v[8];
#pragma unroll
            for (int j = 0; j < 8; ++j) {
                const float iv = 1.f / (1.f + __expf(-gv[0][j]));
                const float fv = 1.f / (1.f + __expf(-gv[1][j]));
                const float gg = tanhf(gv[2][j]);
                const float ov = 1.f / (1.f + __expf(-gv[3][j]));
                const float c0j = (j < 4) ? c0a[j] : c0b[j - 4];
                const float c1 = fv * c0j + iv * gg;
                const float h1 = ov * tanhf(c1);
                c1v[j] = c1;
                h1v[j] = h1;
                hS[r * 128 + uc + j] = (bf16)h1;
            }
            *(f32x4*)(out + O_H1 + (size_t)b * LH + uc) = *(const f32x4*)&h1v[0];
            *(f32x4*)(out + O_H1 + (size_t)b * LH + uc + 4) = *(const f32x4*)&h1v[4];
            *(f32x4*)(out + O_C1 + (size_t)b * LH + uc) = *(const f32x4*)&c1v[0];
            *(f32x4*)(out + O_C1 + (size_t)b * LH + uc + 4) = *(const f32x4*)&c1v[4];
        }
        __syncthreads();

        // --- B: MLP head on wave 0 (verbatim mlp_head, h1 from LDS) ---
        const bf16* W1f = (const bf16*)(ws + OFF_W1F);
        const bf16* W2f = (const bf16*)(ws + OFF_W2F);
        const bf16* Waf = (const bf16*)(ws + OFF_WAF);
        const int nl = t & 15, kg = (t & 63) >> 4;
        const int b0 = bid * 16;

        if (t < 64) {
            bf16x8 ah[4];
#pragma unroll
            for (int kt = 0; kt < 4; ++kt)
                ah[kt] = *(const bf16x8*)&hS[nl * 128 + kt * 32 + kg * 8];
#pragma unroll
            for (int nt = 0; nt < 4; ++nt) {
                f32x4 a = {0.f, 0.f, 0.f, 0.f};
#pragma unroll
                for (int kt = 0; kt < 4; ++kt)
                    a = __builtin_amdgcn_mfma_f32_16x16x32_bf16(
                        ah[kt], *(const bf16x8*)&W1f[((nt * 4 + kt) * 64 + t) * 8],
                        a, 0, 0, 0);
                const int n = nt * 16 + nl;
                const float bb = b1[n];
#pragma unroll
                for (int rr = 0; rr < 4; ++rr)
                    uS[(kg * 4 + rr) * 64 + n] = (bf16)fmaxf(a[rr] + bb, 0.f);
            }
        }
        __syncthreads();

        if (t < 64) {
            bf16x8 au[2];
#pragma unroll
            for (int kt = 0; kt < 2; ++kt)
                au[kt] = *(const bf16x8*)&uS[nl * 64 + kt * 32 + kg * 8];
#pragma unroll
            for (int nt = 0; nt < 8; ++nt) {
                f32x4 a = {0.f, 0.f, 0.f, 0.f};
#pragma unroll
                for (int kt = 0; kt < 2; ++kt)
                    a = __builtin_amdgcn_mfma_f32_16x16x32_bf16(
                        au[kt], *(const bf16x8*)&W2f[((nt * 2 + kt) * 64 + t) * 8],
                        a, 0, 0, 0);
                const int n = nt * 16 + nl;
                const float bb = b2[n];
#pragma unroll
                for (int rr = 0; rr < 4; ++rr)
                    fS[(kg * 4 + rr) * 128 + n] = (bf16)(a[rr] + bb);
            }
        }
        __syncthreads();

        if (t < 64) {
            bf16x8 afr[4];
#pragma unroll
            for (int kt = 0; kt < 4; ++kt)
                afr[kt] = *(const bf16x8*)&fS[nl * 128 + kt * 32 + kg * 8];

            f32x4 lg4 = {0.f, 0.f, 0.f, 0.f};
#pragma unroll
            for (int kt = 0; kt < 4; ++kt)
                lg4 = __builtin_amdgcn_mfma_f32_16x16x32_bf16(
                    afr[kt], *(const bf16x8*)&Waf[(kt * 64 + t) * 8], lg4, 0, 0, 0);

            const float bav = (nl < 9) ? ba[nl] : 0.f;

#pragma unroll
            for (int rr = 0; rr < 4; ++rr) {
                const int b = b0 + kg * 4 + rr;
                float lg = (nl < 9) ? lg4[rr] + bav : -1e30f;
                float mx = lg;
#pragma unroll
                for (int off = 1; off < 16; off <<= 1)
                    mx = fmaxf(mx, __shfl_xor(mx, off, 64));
                const float e = (nl < 9) ? __expf(lg - mx) : 0.f;
                const float mv = (nl < 9) ? mask[(size_t)b * 9 + nl] : 0.f;
                float tot = e, ms = e * mv;
#pragma unroll
                for (int off = 1; off < 16; off <<= 1) {
                    tot += __shfl_xor(tot, off, 64);
                    ms += __shfl_xor(ms, off, 64);
                }
                if (nl < 9)
                    out[(size_t)b * 9 + nl] = (ms > 0.f) ? e * mv / ms : e / tot;
            }
        }
    }
}

// ---------------------------------------------------------------------------
extern "C" void kernel_launch(void* const* d_in, const int* in_sizes, int n_in,
                              void* d_out, int out_size, void* d_ws, size_t ws_size,
                              hipStream_t stream) {
    const int* ab_ids = (const int*)d_in[0];
    const int* mv_ids = (const int*)d_in[1];
    const float* numerical = (const float*)d_in[2];
    const float* mask = (const float*)d_in[3];
    const float* h0 = (const float*)d_in[4];
    const float* c0 = (const float*)d_in[5];
    const float* ab_emb = (const float*)d_in[6];
    const float* mv_emb = (const float*)d_in[7];
    const float* numW = (const float*)d_in[8];
    const float* numb = (const float*)d_in[9];
    const float* Wih = (const float*)d_in[10];
    const float* Whh = (const float*)d_in[11];
    const float* bih = (const float*)d_in[12];
    const float* bhh = (const float*)d_in[13];
    const float* W1 = (const float*)d_in[14];
    const float* b1 = (const float*)d_in[15];
    const float* W2 = (const float*)d_in[16];
    const float* b2 = (const float*)d_in[17];
    const float* Wa = (const float*)d_in[18];
    const float* ba = (const float*)d_in[19];
    float* out = (float*)d_out;
    uint8_t* ws = (uint8_t*)d_ws;

    static int s_coop = -1;
    if (s_coop < 0) {
        int dev = 0;
        hipGetDevice(&dev);
        int v = 0;
        hipDeviceGetAttribute(&v, hipDeviceAttributeCooperativeLaunch, dev);
        s_coop = v;
    }

    bool launched = false;
    if (s_coop) {
        void* args[22] = {
            (void*)&ab_ids, (void*)&mv_ids, (void*)&numerical, (void*)&mask,
            (void*)&h0, (void*)&c0, (void*)&ab_emb, (void*)&mv_emb,
            (void*)&numW, (void*)&numb, (void*)&Wih, (void*)&Whh,
            (void*)&bih, (void*)&bhh, (void*)&W1, (void*)&b1,
            (void*)&W2, (void*)&b2, (void*)&Wa, (void*)&ba,
            (void*)&ws, (void*)&out};
        launched = (hipLaunchCooperativeKernel((const void*)fused, dim3(GRID),
                                               dim3(256), args, 0, stream) ==
                    hipSuccess);
    }

    if (!launched) {
        // fallback: original verified 4-kernel pipeline
        bf16* Wcat = (bf16*)(ws + OFF_WCAT);
        bf16* gpart = (bf16*)(ws + OFF_GPART);
        uint32_t* addrs = (uint32_t*)(ws + OFF_ADDR);
        bf16* h1b = (bf16*)(ws + OFF_H1B);
        bf16* W1f = (bf16*)(ws + OFF_W1F);
        bf16* W2f = (bf16*)(ws + OFF_W2F);
        bf16* Waf = (bf16*)(ws + OFF_WAF);
        float* nbias = (float*)(ws + OFF_NB);

        prep<<<PREP_TOT, 256, 0, stream>>>(
            ab_ids, mv_ids, numerical, h0, numW, numb, Wih, Whh, ab_emb, mv_emb,
            W1, W2, Wa, ws);
        gemm_gates<<<dim3(32, 4, SPLITK), 256, 0, stream>>>(ws, Wcat, addrs, gpart);
        reduce_lstm<<<BATCH / 2, 256, 0, stream>>>(gpart, bih, bhh, nbias, c0,
                                                   out, h1b);
        mlp_head<<<BATCH / 16, 64, 0, stream>>>(h1b, mask, W1f, W2f, Waf,
                                                b1, b2, ba, out);
    }
}

// Round 3
// 168.435 us; speedup vs baseline: 2.4951x; 2.4951x over previous
//
#include <hip/hip_runtime.h>
#include <hip/hip_bf16.h>
#include <stdint.h>
#include <stddef.h>

typedef __bf16 bf16;
typedef __bf16 bf16x4 __attribute__((ext_vector_type(4)));
typedef __bf16 bf16x8 __attribute__((ext_vector_type(8)));
typedef float f32x4 __attribute__((ext_vector_type(4)));

#define BATCH 4096
#define KIH 7808          // Wih K
#define KTOT 7936         // 62 slots * 128 (h0 appended)
#define NG 512            // 4*LH gates
#define LH 128
#define HD 64
#define ED 128
#define SPLITK 4

// workspace layout (byte offsets)
#define OFF_WCAT 0u                 //  8,126,464  bf16 Wcat[512][7936]
#define OFF_GPART 8126464u          // 16,777,216  bf16 gpart[4][4096][512]
#define OFF_XT   24903680u          //  2,097,152  bf16 xtail[4096][256]
#define OFF_AB   27000832u          //     76,800  bf16 ab8[300][128]
#define OFF_MV   27077632u          //    230,400  bf16 mv8[900][128]
#define OFF_ADDR 27308032u          //  1,048,576  u32 addrs[4096][64]
#define OFF_W1F  29405184u          //     16,384  bf16 W1 fragments
#define OFF_W2F  29421568u          //     16,384  bf16 W2 fragments
#define OFF_WAF  29437952u          //      4,096  bf16 Wa fragments
#define OFF_NB   29442048u          //      2,048  f32 nbias[512]
// end: 29,444,096 B

// out layout: probs[B*9] | h1[B*128] | c1[B*128]
#define O_H1 (BATCH * 9)
#define O_C1 (BATCH * 9 + BATCH * LH)

// prep grid partition
#define PREP_BP 2048                 // build_pre: 2 rows/block
#define PREP_CW (PREP_BP + 512)      // convert_w
#define PREP_CE (PREP_CW + 150)      // convert_emb (float4 x 256 x 150 = 153600)
#define PREP_TOT (PREP_CE + 1)       // + MLP fragment pack

// ---------------------------------------------------------------------------
typedef const __attribute__((address_space(1))) uint32_t* gas_ptr;
typedef __attribute__((address_space(3))) uint32_t* las_ptr;

__device__ __forceinline__ void async16(const void* g, void* l) {
    __builtin_amdgcn_global_load_lds((gas_ptr)g, (las_ptr)l, 16, 0, 0);
}

// ---------------------------------------------------------------------------
// Kernel 1: fused prep (verbatim from the verified 167us version).
// ---------------------------------------------------------------------------
__global__ void prep(const int* __restrict__ ab_ids,
                     const int* __restrict__ mv_ids,
                     const float* __restrict__ numerical,
                     const float* __restrict__ h0,
                     const float* __restrict__ numW,
                     const float* __restrict__ numb,
                     const float* __restrict__ Wih,
                     const float* __restrict__ Whh,
                     const float* __restrict__ ab_emb,
                     const float* __restrict__ mv_emb,
                     const float* __restrict__ W1,
                     const float* __restrict__ W2,
                     const float* __restrict__ Wa,
                     uint8_t* __restrict__ ws) {
    const int bid = blockIdx.x;
    const int t = threadIdx.x;  // 0..255

    if (bid < PREP_BP) {
        // ---- build_pre: 2 rows per block; half-block (128 thr) per row ----
        bf16* xtail = (bf16*)(ws + OFF_XT);
        uint32_t* addrs = (uint32_t*)(ws + OFF_ADDR);
        const int h = t >> 7;            // row half 0/1
        const int th = t & 127;
        const int b = bid * 2 + h;

        __shared__ int ids[2][60];
        if (th < 60)
            ids[h][th] = (th < 12) ? ab_ids[b * 12 + th]
                                   : mv_ids[b * 48 + (th - 12)];

        const float v = (th < 84) ? numerical[(size_t)b * 84 + th] : 0.f;
        xtail[(size_t)b * 256 + th] = (bf16)v;
        xtail[(size_t)b * 256 + 128 + th] = (bf16)h0[(size_t)b * LH + th];
        __syncthreads();

        if (th < 64) {
            uint32_t off;
            if (th < 12) off = OFF_AB + (uint32_t)ids[h][th] * 256u;
            else if (th < 60) off = OFF_MV + (uint32_t)ids[h][th] * 256u;
            else if (th == 60) off = OFF_XT + (uint32_t)b * 512u;
            else if (th == 61) off = OFF_XT + (uint32_t)b * 512u + 256u;
            else off = OFF_XT;  // unused slots 62,63
            addrs[(size_t)b * 64 + th] = off;
        }
    } else if (bid < PREP_CW) {
        // ---- convert_w: cols [0,7680) direct; slot 60 = Wfold; then Whh ----
        bf16* Wcat = (bf16*)(ws + OFF_WCAT);
        float* nbias = (float*)(ws + OFF_NB);
        const int n = bid - PREP_BP;

        __shared__ float wrow[128];   // Wih[n][7680..7808)
        __shared__ float nbs[128];
        if (t < 128) wrow[t] = Wih[(size_t)n * KIH + 7680 + t];
        else nbs[t - 128] = numb[t - 128];
        __syncthreads();

        const float* src_ih = Wih + (size_t)n * KIH;
        bf16* dst = Wcat + (size_t)n * KTOT;
        for (int k4 = t; k4 < 1920; k4 += 256) {   // 7680/4
            const int k = k4 * 4;
            const float4 v = *(const float4*)(src_ih + k);
            bf16x4 o = {(bf16)v.x, (bf16)v.y, (bf16)v.z, (bf16)v.w};
            *(bf16x4*)(dst + k) = o;
        }
        if (t < 84) {
            // Wfold[n][t] = sum_e Wih[n][7680+e] * numW[e][t]
            float acc = 0.f;
#pragma unroll 4
            for (int e = 0; e < 128; ++e)
                acc += wrow[e] * numW[e * 84 + t];
            dst[7680 + t] = (bf16)acc;
        } else if (t < 128) {
            dst[7680 + t] = (bf16)0.f;     // padding cols (x is zero there too)
        } else {
            const int tt = t - 128;
            dst[KIH + tt] = (bf16)Whh[(size_t)n * LH + tt];
        }
        if (t == 255) {
            float a = 0.f;
#pragma unroll 4
            for (int e = 0; e < 128; ++e) a += wrow[e] * nbs[e];
            nbias[n] = a;
        }
    } else if (bid < PREP_CE) {
        // ---- convert_emb: 4 elems/thread, float4 -> bf16x4 ----
        bf16* ab8 = (bf16*)(ws + OFF_AB);
        bf16* mv8 = (bf16*)(ws + OFF_MV);
        const int i = ((bid - PREP_CW) * 256 + t) * 4;   // 0..153596
        const bool isab = i < 300 * 128;
        const float4 v = isab ? *(const float4*)(ab_emb + i)
                              : *(const float4*)(mv_emb + (i - 300 * 128));
        bf16x4 o = {(bf16)v.x, (bf16)v.y, (bf16)v.z, (bf16)v.w};
        if (isab) *(bf16x4*)(ab8 + i) = o;
        else *(bf16x4*)(mv8 + (i - 300 * 128)) = o;
    } else {
        // ---- pack MLP weight fragments (B-frag: lane n=l&15, k=(l>>4)*8+j) --
        bf16* W1f = (bf16*)(ws + OFF_W1F);
        bf16* W2f = (bf16*)(ws + OFF_W2F);
        bf16* Waf = (bf16*)(ws + OFF_WAF);
        for (int e = t; e < 8192; e += 256) {     // W1 (64x128), fid = nt*4+kt
            const int j = e & 7, ln = (e >> 3) & 63, fid = e >> 9;
            const int kt = fid & 3, nt = fid >> 2;
            const int n = nt * 16 + (ln & 15);
            const int k = kt * 32 + (ln >> 4) * 8 + j;
            W1f[e] = (bf16)W1[n * 128 + k];
        }
        for (int e = t; e < 8192; e += 256) {     // W2 (128x64), fid = nt*2+kt
            const int j = e & 7, ln = (e >> 3) & 63, fid = e >> 9;
            const int kt = fid & 1, nt = fid >> 1;
            const int n = nt * 16 + (ln & 15);
            const int k = kt * 32 + (ln >> 4) * 8 + j;
            W2f[e] = (bf16)W2[n * 64 + k];
        }
        for (int e = t; e < 2048; e += 256) {     // Wa (9x128 zero-padded)
            const int j = e & 7, ln = (e >> 3) & 63, kt = e >> 9;
            const int n = ln & 15;
            const int k = kt * 32 + (ln >> 4) * 8 + j;
            Waf[e] = (n < 9) ? (bf16)Wa[n * 128 + k] : (bf16)0.f;
        }
    }
}

// ---------------------------------------------------------------------------
// Kernel 2: gpart[bz] = x @ Wcat.T partial  (x gathered on the fly)
// 128x128 block tile, BK=64, XOR-swizzled LDS, double-buffered, split-K=4.
// XCD-aware block remap (T1). Launched 1-D with 512 blocks; hardware
// round-robins bid%8 across the 8 XCDs, so we pin each XCD to ONE Wcat
// bn-panel (2 MB -> L2-resident) and spread (bm,bz) within the XCD.
// Bijective: 512 blocks = 8 xcd * 64 slot; combo = (xcd>>2)*64+slot covers
// bm 0..31 x bz 0..3 exactly once per bn.
// ---------------------------------------------------------------------------
__global__ __launch_bounds__(256, 2) void gemm_gates(
    const uint8_t* __restrict__ wsbase,
    const bf16* __restrict__ Wcat,
    const uint32_t* __restrict__ addrs,
    bf16* __restrict__ gpart) {
    __shared__ bf16 As[2][128 * 64];    // 2 x 16 KB
    __shared__ bf16 Bs[2][128 * 64];    // 2 x 16 KB
    __shared__ uint32_t adr[17][128];   // 8.5 KB

    const int tid = threadIdx.x;
    const int w = tid >> 6;       // wave 0..3
    const int lane = tid & 63;

    const int bid = blockIdx.x;   // 0..511
    const int xcd = bid & 7;
    const int slot = bid >> 3;               // 0..63
    const int bn = xcd & 3;                  // XCD-pinned Wcat panel
    const int combo = ((xcd >> 2) << 6) + slot;  // 0..127
    const int bm = combo & 31;
    const int bz = combo >> 5;

    const int kt_beg = bz * 31;
    const int kt_end = kt_beg + 31;

    // preload this block's (row, slot) offsets
    const int s0 = kt_beg >> 1;
    const int ns = ((kt_end - 1) >> 1) - s0 + 1;   // <= 17
    for (int i = tid; i < ns * 128; i += 256) {
        adr[i >> 7][i & 127] =
            addrs[(size_t)(bm * 128 + (i & 127)) * 64 + s0 + (i >> 7)];
    }

    const int r_l = lane >> 3;                  // staging row within 8-row group
    const int sc16 = ((lane & 7) ^ r_l) * 16;   // XOR-swizzled 16B chunk (bytes)

    const int wn = w & 1;         // n-half: cols wn*64 .. wn*64+63
    const int wk = w >> 1;        // k-slice: elems wk*32 .. wk*32+31 of each BK
    const int n0 = wn * 64;
    const int kk8 = wk * 4 + (lane >> 4);       // global column chunk for frags
    const int fl = lane & 15;

    f32x4 acc[8][4];
#pragma unroll
    for (int i = 0; i < 8; ++i)
#pragma unroll
        for (int j = 0; j < 4; ++j)
#pragma unroll
            for (int r = 0; r < 4; ++r) acc[i][j][r] = 0.f;

    __syncthreads();  // adr visible

    auto stage = [&](int kt, int pb) {
        const int k0 = kt * 64;
        const int sl = (kt >> 1) - s0;
        const int hb = (kt & 1) * 128;
#pragma unroll
        for (int j = 0; j < 4; ++j) {
            const int row = (w * 4 + j) * 8 + r_l;
            const uint8_t* gsrc = wsbase + adr[sl][row] + hb + sc16;
            async16(gsrc, (void*)&As[pb][((w * 4 + j) * 64 + lane) * 8]);
        }
#pragma unroll
        for (int j = 0; j < 4; ++j) {
            const int row = (w * 4 + j) * 8 + r_l;
            const bf16* gsrc = Wcat + (size_t)(bn * 128 + row) * KTOT + k0 + (sc16 >> 1);
            async16(gsrc, (void*)&Bs[pb][((w * 4 + j) * 64 + lane) * 8]);
        }
    };

    stage(kt_beg, 0);   // prologue into buffer 0

    for (int kt = kt_beg; kt < kt_end; ++kt) {
        const int pb = (kt - kt_beg) & 1;
        __syncthreads();
        if (kt + 1 < kt_end) stage(kt + 1, pb ^ 1);

        const bf16* Ab = &As[pb][0];
        const bf16* Bb = &Bs[pb][0];

        bf16x8 bfr[4];
#pragma unroll
        for (int tj = 0; tj < 4; ++tj) {
            const int n = n0 + tj * 16 + fl;
            bfr[tj] = *(const bf16x8*)&Bb[n * 64 + ((kk8 ^ (n & 7)) * 8)];
        }
#pragma unroll
        for (int ti = 0; ti < 8; ++ti) {
            const int m = ti * 16 + fl;
            const bf16x8 af = *(const bf16x8*)&Ab[m * 64 + ((kk8 ^ (m & 7)) * 8)];
#pragma unroll
            for (int tj = 0; tj < 4; ++tj)
                acc[ti][tj] = __builtin_amdgcn_mfma_f32_16x16x32_bf16(
                    af, bfr[tj], acc[ti][tj], 0, 0, 0);
        }
    }

    // ---- reduce wk-partials through LDS (As/Bs are dead now) ----
    __syncthreads();
    float* red = (wn == 0) ? (float*)&As[0][0] : (float*)&Bs[0][0];  // 32 KB each
    if (wk == 1) {
#pragma unroll
        for (int ti = 0; ti < 8; ++ti)
#pragma unroll
            for (int tj = 0; tj < 4; ++tj)
#pragma unroll
                for (int r = 0; r < 4; ++r)
                    red[((ti * 4 + tj) * 4 + r) * 64 + lane] = acc[ti][tj][r];
    }
    __syncthreads();

    if (wk == 0) {
        bf16* gdst = gpart + (size_t)bz * BATCH * NG;
        const int mlo = (lane >> 4) * 4;
#pragma unroll
        for (int ti = 0; ti < 8; ++ti)
#pragma unroll
            for (int tj = 0; tj < 4; ++tj) {
                const int mg = bm * 128 + ti * 16 + mlo;
                const int ng = bn * 128 + n0 + tj * 16 + fl;
                bf16* dst = gdst + (size_t)mg * NG + ng;
#pragma unroll
                for (int r = 0; r < 4; ++r)
                    dst[(size_t)r * NG] = (bf16)(
                        acc[ti][tj][r] + red[((ti * 4 + tj) * 4 + r) * 64 + lane]);
            }
    }
}

// ---------------------------------------------------------------------------
// Kernel 3: fused tail = split-K reduce + LSTM pointwise + MLP head.
// 256 blocks x 256 threads, 16 batch rows per block.
//   phase A (all 4 waves): vectorized bf16x8 gate reduction, LSTM, h1 -> LDS
//   phase B (wave 0): 3-stage MFMA MLP + softmax + masked renorm.
// Block-local only -- no grid-wide dependency (each block's MLP rows are
// exactly the rows its phase A produced). Logic identical to the verified
// round-1 fused-kernel tail phase.
// ---------------------------------------------------------------------------
__global__ __launch_bounds__(256) void tail(
    const bf16* __restrict__ gpart,
    const float* __restrict__ bih, const float* __restrict__ bhh,
    const float* __restrict__ nbias, const float* __restrict__ c0,
    const float* __restrict__ mask,
    const bf16* __restrict__ W1f, const bf16* __restrict__ W2f,
    const bf16* __restrict__ Waf,
    const float* __restrict__ b1, const float* __restrict__ b2,
    const float* __restrict__ ba,
    float* __restrict__ out) {
    __shared__ bf16 hS[16 * 128];    // 4 KB
    __shared__ bf16 uS[16 * 64];     // 2 KB
    __shared__ bf16 fS[16 * 128];    // 4 KB

    const int t = threadIdx.x;
    const int bid = blockIdx.x;
    const int b0 = bid * 16;

    // --- phase A: gate reduction + LSTM, 8 units/thread ---
    {
        const int r = t >> 4;               // row 0..15
        const int uc = (t & 15) * 8;        // unit chunk
        const int b = b0 + r;

        float gv[4][8];
#pragma unroll
        for (int q = 0; q < 4; ++q)
#pragma unroll
            for (int hh = 0; hh < 2; ++hh) {
                const f32x4 va = *(const f32x4*)(bih + q * 128 + uc + hh * 4);
                const f32x4 vb = *(const f32x4*)(bhh + q * 128 + uc + hh * 4);
                const f32x4 vn = *(const f32x4*)(nbias + q * 128 + uc + hh * 4);
#pragma unroll
                for (int j = 0; j < 4; ++j)
                    gv[q][hh * 4 + j] = va[j] + vb[j] + vn[j];
            }
#pragma unroll
        for (int z = 0; z < SPLITK; ++z) {
            const bf16* gz = gpart + ((size_t)z * BATCH + b) * NG;
#pragma unroll
            for (int q = 0; q < 4; ++q) {
                const bf16x8 v = *(const bf16x8*)(gz + q * 128 + uc);
#pragma unroll
                for (int j = 0; j < 8; ++j) gv[q][j] += (float)v[j];
            }
        }

        const f32x4 c0a = *(const f32x4*)(c0 + (size_t)b * LH + uc);
        const f32x4 c0b = *(const f32x4*)(c0 + (size_t)b * LH + uc + 4);
        float h1v[8], c1v[8];
        bf16x8 hv8;
#pragma unroll
        for (int j = 0; j < 8; ++j) {
            const float iv = 1.f / (1.f + __expf(-gv[0][j]));
            const float fv = 1.f / (1.f + __expf(-gv[1][j]));
            const float gg = tanhf(gv[2][j]);
            const float ov = 1.f / (1.f + __expf(-gv[3][j]));
            const float c0j = (j < 4) ? c0a[j] : c0b[j - 4];
            const float c1 = fv * c0j + iv * gg;
            const float h1 = ov * tanhf(c1);
            c1v[j] = c1;
            h1v[j] = h1;
            hv8[j] = (bf16)h1;
        }
        *(bf16x8*)&hS[r * 128 + uc] = hv8;
        *(f32x4*)(out + O_H1 + (size_t)b * LH + uc) = *(const f32x4*)&h1v[0];
        *(f32x4*)(out + O_H1 + (size_t)b * LH + uc + 4) = *(const f32x4*)&h1v[4];
        *(f32x4*)(out + O_C1 + (size_t)b * LH + uc) = *(const f32x4*)&c1v[0];
        *(f32x4*)(out + O_C1 + (size_t)b * LH + uc + 4) = *(const f32x4*)&c1v[4];
    }
    __syncthreads();

    // --- phase B: MLP head on wave 0 (verbatim verified mlp_head) ---
    const int nl = t & 15, kg = (t & 63) >> 4;

    if (t < 64) {
        bf16x8 ah[4];
#pragma unroll
        for (int kt = 0; kt < 4; ++kt)
            ah[kt] = *(const bf16x8*)&hS[nl * 128 + kt * 32 + kg * 8];
#pragma unroll
        for (int nt = 0; nt < 4; ++nt) {
            f32x4 a = {0.f, 0.f, 0.f, 0.f};
#pragma unroll
            for (int kt = 0; kt < 4; ++kt)
                a = __builtin_amdgcn_mfma_f32_16x16x32_bf16(
                    ah[kt], *(const bf16x8*)&W1f[((nt * 4 + kt) * 64 + t) * 8],
                    a, 0, 0, 0);
            const int n = nt * 16 + nl;
            const float bb = b1[n];
#pragma unroll
            for (int rr = 0; rr < 4; ++rr)
                uS[(kg * 4 + rr) * 64 + n] = (bf16)fmaxf(a[rr] + bb, 0.f);
        }
    }
    __syncthreads();

    if (t < 64) {
        bf16x8 au[2];
#pragma unroll
        for (int kt = 0; kt < 2; ++kt)
            au[kt] = *(const bf16x8*)&uS[nl * 64 + kt * 32 + kg * 8];
#pragma unroll
        for (int nt = 0; nt < 8; ++nt) {
            f32x4 a = {0.f, 0.f, 0.f, 0.f};
#pragma unroll
            for (int kt = 0; kt < 2; ++kt)
                a = __builtin_amdgcn_mfma_f32_16x16x32_bf16(
                    au[kt], *(const bf16x8*)&W2f[((nt * 2 + kt) * 64 + t) * 8],
                    a, 0, 0, 0);
            const int n = nt * 16 + nl;
            const float bb = b2[n];
#pragma unroll
            for (int rr = 0; rr < 4; ++rr)
                fS[(kg * 4 + rr) * 128 + n] = (bf16)(a[rr] + bb);
        }
    }
    __syncthreads();

    if (t < 64) {
        bf16x8 afr[4];
#pragma unroll
        for (int kt = 0; kt < 4; ++kt)
            afr[kt] = *(const bf16x8*)&fS[nl * 128 + kt * 32 + kg * 8];

        f32x4 lg4 = {0.f, 0.f, 0.f, 0.f};
#pragma unroll
        for (int kt = 0; kt < 4; ++kt)
            lg4 = __builtin_amdgcn_mfma_f32_16x16x32_bf16(
                afr[kt], *(const bf16x8*)&Waf[(kt * 64 + t) * 8], lg4, 0, 0, 0);

        const float bav = (nl < 9) ? ba[nl] : 0.f;

#pragma unroll
        for (int rr = 0; rr < 4; ++rr) {
            const int b = b0 + kg * 4 + rr;
            float lg = (nl < 9) ? lg4[rr] + bav : -1e30f;
            float mx = lg;
#pragma unroll
            for (int off = 1; off < 16; off <<= 1)
                mx = fmaxf(mx, __shfl_xor(mx, off, 64));
            const float e = (nl < 9) ? __expf(lg - mx) : 0.f;
            const float mv = (nl < 9) ? mask[(size_t)b * 9 + nl] : 0.f;
            float tot = e, ms = e * mv;
#pragma unroll
            for (int off = 1; off < 16; off <<= 1) {
                tot += __shfl_xor(tot, off, 64);
                ms += __shfl_xor(ms, off, 64);
            }
            if (nl < 9)
                out[(size_t)b * 9 + nl] = (ms > 0.f) ? e * mv / ms : e / tot;
        }
    }
}

// ---------------------------------------------------------------------------
extern "C" void kernel_launch(void* const* d_in, const int* in_sizes, int n_in,
                              void* d_out, int out_size, void* d_ws, size_t ws_size,
                              hipStream_t stream) {
    const int* ab_ids = (const int*)d_in[0];
    const int* mv_ids = (const int*)d_in[1];
    const float* numerical = (const float*)d_in[2];
    const float* mask = (const float*)d_in[3];
    const float* h0 = (const float*)d_in[4];
    const float* c0 = (const float*)d_in[5];
    const float* ab_emb = (const float*)d_in[6];
    const float* mv_emb = (const float*)d_in[7];
    const float* numW = (const float*)d_in[8];
    const float* numb = (const float*)d_in[9];
    const float* Wih = (const float*)d_in[10];
    const float* Whh = (const float*)d_in[11];
    const float* bih = (const float*)d_in[12];
    const float* bhh = (const float*)d_in[13];
    const float* W1 = (const float*)d_in[14];
    const float* b1 = (const float*)d_in[15];
    const float* W2 = (const float*)d_in[16];
    const float* b2 = (const float*)d_in[17];
    const float* Wa = (const float*)d_in[18];
    const float* ba = (const float*)d_in[19];
    float* out = (float*)d_out;

    uint8_t* ws = (uint8_t*)d_ws;
    bf16* Wcat = (bf16*)(ws + OFF_WCAT);
    bf16* gpart = (bf16*)(ws + OFF_GPART);
    uint32_t* addrs = (uint32_t*)(ws + OFF_ADDR);
    bf16* W1f = (bf16*)(ws + OFF_W1F);
    bf16* W2f = (bf16*)(ws + OFF_W2F);
    bf16* Waf = (bf16*)(ws + OFF_WAF);
    float* nbias = (float*)(ws + OFF_NB);

    prep<<<PREP_TOT, 256, 0, stream>>>(
        ab_ids, mv_ids, numerical, h0, numW, numb, Wih, Whh, ab_emb, mv_emb,
        W1, W2, Wa, ws);
    gemm_gates<<<512, 256, 0, stream>>>(ws, Wcat, addrs, gpart);
    tail<<<BATCH / 16, 256, 0, stream>>>(gpart, bih, bhh, nbias, c0, mask,
                                         W1f, W2f, Waf, b1, b2, ba, out);
}